// Round 5
// baseline (542.408 us; speedup 1.0000x reference)
//
#include <hip/hip_runtime.h>
#include <stdint.h>
#include <stddef.h>

// SplitConv4Pim forward on MI355X.
// R5 = R2's 2-phase / 16-waves-per-CU structure + fragment-major (conflict-free)
// LDS layout + interleaved XCD swizzle.
// ws layout: [wq bf16: 4,718,592 B][xt bf16: 27,557,888 B]

typedef __bf16 bf16_t;
typedef __bf16 bf16x8 __attribute__((ext_vector_type(8)));
typedef float  f32x4  __attribute__((ext_vector_type(4)));

#define WS_XT_OFF 4718592

__device__ __forceinline__ void gload16(const void* g, void* l) {
  __builtin_amdgcn_global_load_lds(
      (const __attribute__((address_space(1))) uint32_t*)g,
      (__attribute__((address_space(3))) uint32_t*)l, 16, 0, 0);
}

// ---- P1: weight quantization: w[o][ic][ky][kx] f32 -> wq[o][kpos][ic] bf16 ----
__global__ void quant_w_k(const float* __restrict__ w,
                          const float* __restrict__ wsc,
                          bf16_t* __restrict__ wqo) {
  int idx = blockIdx.x * 256 + threadIdx.x;   // 1024*9*256 threads
  int ic   = idx & 255;
  int t2   = idx >> 8;
  int kpos = t2 % 9;
  int o    = t2 / 9;
  float s  = wsc[ic >> 5];
  float wv = w[o * 2304 + ic * 9 + kpos];
  float wi = rintf(wv / s);
  wi = fminf(127.f, fmaxf(-128.f, wi));
  int u = (int)wi + 128;
  int q = (u >> 6) & 3;
  float wsplit = (float)(q * 64 - 128);
  wqo[idx] = (bf16_t)(wsplit * s);
}

// ---- P2: x NCHW f32 -> padded NHWC bf16 xt[16][58][58][256] ----
__global__ void pad_x_k(const float* __restrict__ x, bf16_t* __restrict__ xt) {
  __shared__ bf16_t tile[56 * 258];
  int b  = blockIdx.x / 58;
  int yo = blockIdx.x % 58;
  int t  = threadIdx.x;
  bf16_t* dst = xt + (size_t)(b * 58 + yo) * 58 * 256;
  if (yo == 0 || yo == 57) {
    for (int i = 0; i < 58; ++i) dst[i * 256 + t] = (bf16_t)0.0f;
    return;
  }
  const float* src = x + (size_t)b * 256 * 3136 + (yo - 1) * 56;
  for (int i = 0; i < 56 * 256; i += 256) {
    int lin = i + t;
    int c  = lin / 56;
    int xx = lin - c * 56;
    tile[xx * 258 + c] = (bf16_t)src[c * 3136 + xx];
  }
  __syncthreads();
  for (int xo = 0; xo < 58; ++xo) {
    bf16_t v = (bf16_t)0.0f;
    if (xo >= 1 && xo <= 56) v = tile[(xo - 1) * 258 + t];
    dst[xo * 256 + t] = v;
  }
}

// ---- main: implicit-GEMM conv + per-group psum quant + group sum ----
// grid 784 = 392 m-tiles x 2 oc-halves; 512 threads (8 waves: 2 oc x 4 m, 64x32 each).
// BK=64 as two 32-k half-panels. LDS fragment-major: [8 frag][64 lane][16B] per panel
// -> every wave ds_read_b128 covers 64 consecutive 16B chunks (conflict-free).
__global__ __launch_bounds__(512, 4)
void conv_q_k(const bf16_t* __restrict__ xt, const bf16_t* __restrict__ wq,
              const float* __restrict__ ps, float* __restrict__ out) {
  __shared__ alignas(16) bf16_t Ab[2][2][4096];  // [buf][half][frag-major 8KB]
  __shared__ alignas(16) bf16_t Bb[2][2][4096];

  const int tid  = threadIdx.x;
  const int lane = tid & 63;
  const int wave = tid >> 6;

  // XCD swizzle (784 = 8 x 98), interleaved (mt, ocblk): each XCD gets 49
  // consecutive m-tiles (both oc halves) -> x slice ~3.2 MB L2-resident.
  const int bid   = blockIdx.x;
  const int s     = (bid & 7) * 98 + (bid >> 3);
  const int mt    = s >> 1;
  const int ocblk = s & 1;
  const int m0    = mt << 7;
  const int n0    = ocblk << 7;

  // ---- staging: thread t stages chunk t of each 8 KB half-panel ----
  // chunk t: frag f = t>>6, lane-in-frag l = t&63 holds
  //   row 16f+(l&15), k-elems (l>>4)*8 .. +7   (the exact MFMA fragment slot)
  const int sf = tid >> 6;                    // frag 0..7
  const int sl = tid & 63;
  const int srowA = n0 + 16 * sf + (sl & 15); // oc row this thread stages
  const int skoff = ((sl >> 4) & 3) << 3;     // k-elem offset within 32-k panel
  const int aBase = srowA * 2304 + skoff;     // + g*589824 + kpos*256 + (kk&3)*64 + h*32
  int xBase;                                  // + ((ky*58+kx)<<8) + (kk&3)*64 + h*32
  {
    int gm = m0 + 16 * sf + (sl & 15);
    int b = gm / 3136, rem = gm - b * 3136;
    int oy = rem / 56, ox = rem - oy * 56;
    xBase = ((b * 58 + oy) * 58 + ox) * 256 + skoff;
  }
  char* const ldA = (char*)&Ab[0][0][0] + (tid << 4);
  char* const ldB = (char*)&Bb[0][0][0] + (tid << 4);

  // ---- compute mapping: wave = (wr: 2 oc-halves) x (wc: 4 m-quarters), 64oc x 32m ----
  const int wr = wave >> 2, wc = wave & 3;
  const int aRd = (wr * 4) * 64 + lane;       // frag-major elem idx /8 ; +i*64
  const int bRd = (wc * 2) * 64 + lane;       // +j*64

  f32x4 acc[4][2], oacc[4][2];
#pragma unroll
  for (int i = 0; i < 4; ++i)
#pragma unroll
    for (int j = 0; j < 2; ++j)
#pragma unroll
      for (int k = 0; k < 4; ++k) { acc[i][j][k] = 0.f; oacc[i][j][k] = 0.f; }

  // kk in [0,36): kpos = kk>>2 (tap 0..8), ic64-block = kk&3
  auto STAGE = [&](int gg, int kk, int buf) {
    const int kpos = kk >> 2;
    const int ky = kpos / 3;
    const int kx = kpos - ky * 3;
    const int cm = (kk & 3) << 6;
    const int wb = aBase + gg * 589824 + kpos * 256 + cm;
    const int xb = xBase + ((ky * 58 + kx) << 8) + cm;
    char* la = ldA + buf * 16384;
    char* lb = ldB + buf * 16384;
    gload16(wq + wb,      la);                // A half 0 (k 0..31)
    gload16(wq + wb + 32, la + 8192);         // A half 1 (k 32..63)
    gload16(xt + xb,      lb);                // B half 0
    gload16(xt + xb + 32, lb + 8192);         // B half 1
  };

  STAGE(0, 0, 0);

#pragma unroll 1
  for (int g = 0; g < 4; ++g) {
#pragma unroll 2
    for (int kk = 0; kk < 36; ++kk) {
      const int buf = kk & 1;
      __syncthreads();                        // drains vmcnt: buf staged, buf^1 free
      if (kk + 1 < 36)      STAGE(g, kk + 1, buf ^ 1);
      else if (g < 3)       STAGE(g + 1, 0, buf ^ 1);
#pragma unroll
      for (int h = 0; h < 2; ++h) {
        const bf16_t* Abase = &Ab[buf][h][0];
        const bf16_t* Bbase = &Bb[buf][h][0];
        bf16x8 av[4], bv[2];
#pragma unroll
        for (int i = 0; i < 4; ++i) av[i] = *(const bf16x8*)(Abase + ((aRd + i * 64) << 3));
#pragma unroll
        for (int j = 0; j < 2; ++j) bv[j] = *(const bf16x8*)(Bbase + ((bRd + j * 64) << 3));
#pragma unroll
        for (int i = 0; i < 4; ++i)
#pragma unroll
          for (int j = 0; j < 2; ++j)
            acc[i][j] = __builtin_amdgcn_mfma_f32_16x16x32_bf16(av[i], bv[j], acc[i][j], 0, 0, 0);
      }
    }
    // per-group psum quantize, accumulate into output regs, reset psum
    const float sp  = ps[g];
    const float isp = 1.0f / sp;
#pragma unroll
    for (int i = 0; i < 4; ++i)
#pragma unroll
      for (int j = 0; j < 2; ++j)
#pragma unroll
        for (int k = 0; k < 4; ++k) {
          float q = rintf(acc[i][j][k] * isp);
          q = fminf(127.f, fmaxf(-128.f, q));
          oacc[i][j][k] += q * sp;
          acc[i][j][k] = 0.f;
        }
  }

  // ---- store: D layout col=lane&15 (m), row=(lane>>4)*4+k (oc) ----
  const int rr  = lane & 15;
  const int ocb = n0 + wr * 64 + ((lane >> 4) << 2);
#pragma unroll
  for (int j = 0; j < 2; ++j) {
    int m = m0 + wc * 32 + j * 16 + rr;
    int b = m / 3136, rem = m - b * 3136;
    int oy = rem / 56, ox = rem - oy * 56;
    int obase = b * 802816 + oy * 56 + ox;
#pragma unroll
    for (int i = 0; i < 4; ++i)
#pragma unroll
      for (int k = 0; k < 4; ++k)
        out[obase + (ocb + i * 16 + k) * 3136] = oacc[i][j][k];
  }
}

extern "C" void kernel_launch(void* const* d_in, const int* in_sizes, int n_in,
                              void* d_out, int out_size, void* d_ws, size_t ws_size,
                              hipStream_t stream) {
  const float* x   = (const float*)d_in[0];   // [16,256,56,56]
  const float* w   = (const float*)d_in[1];   // [1024,256,3,3]
  const float* wsc = (const float*)d_in[2];   // [8]
  const float* ps  = (const float*)d_in[3];   // [4]
  float* out = (float*)d_out;                 // [16,256,56,56]
  bf16_t* wq = (bf16_t*)d_ws;
  bf16_t* xt = (bf16_t*)((char*)d_ws + WS_XT_OFF);

  quant_w_k<<<9216, 256, 0, stream>>>(w, wsc, wq);
  pad_x_k<<<16 * 58, 256, 0, stream>>>(x, xt);
  conv_q_k<<<784, 512, 0, stream>>>(xt, wq, ps, out);
}

// Round 6
// 286.048 us; speedup vs baseline: 1.8962x; 1.8962x over previous
//
#include <hip/hip_runtime.h>
#include <stdint.h>
#include <stddef.h>

// SplitConv4Pim forward on MI355X.
// R6 = R2's 2-phase / 16-waves-per-CU structure + BK=64 128B-row panels with
// both-sides XOR slot swizzle (coalesced staging AND conflict-free ds_read)
// + interleaved XCD swizzle (R5's, FETCH 55 MB).
// ws layout: [wq bf16: 4,718,592 B][xt bf16: 27,557,888 B]

typedef __bf16 bf16_t;
typedef __bf16 bf16x8 __attribute__((ext_vector_type(8)));
typedef float  f32x4  __attribute__((ext_vector_type(4)));

#define WS_XT_OFF 4718592

__device__ __forceinline__ void gload16(const void* g, void* l) {
  __builtin_amdgcn_global_load_lds(
      (const __attribute__((address_space(1))) uint32_t*)g,
      (__attribute__((address_space(3))) uint32_t*)l, 16, 0, 0);
}

// ---- P1: weight quantization: w[o][ic][ky][kx] f32 -> wq[o][kpos][ic] bf16 ----
__global__ void quant_w_k(const float* __restrict__ w,
                          const float* __restrict__ wsc,
                          bf16_t* __restrict__ wqo) {
  int idx = blockIdx.x * 256 + threadIdx.x;   // 1024*9*256 threads
  int ic   = idx & 255;
  int t2   = idx >> 8;
  int kpos = t2 % 9;
  int o    = t2 / 9;
  float s  = wsc[ic >> 5];
  float wv = w[o * 2304 + ic * 9 + kpos];
  float wi = rintf(wv / s);
  wi = fminf(127.f, fmaxf(-128.f, wi));
  int u = (int)wi + 128;
  int q = (u >> 6) & 3;
  float wsplit = (float)(q * 64 - 128);
  wqo[idx] = (bf16_t)(wsplit * s);
}

// ---- P2: x NCHW f32 -> padded NHWC bf16 xt[16][58][58][256] ----
__global__ void pad_x_k(const float* __restrict__ x, bf16_t* __restrict__ xt) {
  __shared__ bf16_t tile[56 * 258];
  int b  = blockIdx.x / 58;
  int yo = blockIdx.x % 58;
  int t  = threadIdx.x;
  bf16_t* dst = xt + (size_t)(b * 58 + yo) * 58 * 256;
  if (yo == 0 || yo == 57) {
    for (int i = 0; i < 58; ++i) dst[i * 256 + t] = (bf16_t)0.0f;
    return;
  }
  const float* src = x + (size_t)b * 256 * 3136 + (yo - 1) * 56;
  for (int i = 0; i < 56 * 256; i += 256) {
    int lin = i + t;
    int c  = lin / 56;
    int xx = lin - c * 56;
    tile[xx * 258 + c] = (bf16_t)src[c * 3136 + xx];
  }
  __syncthreads();
  for (int xo = 0; xo < 58; ++xo) {
    bf16_t v = (bf16_t)0.0f;
    if (xo >= 1 && xo <= 56) v = tile[(xo - 1) * 258 + t];
    dst[xo * 256 + t] = v;
  }
}

// ---- main: implicit-GEMM conv + per-group psum quant + group sum ----
// grid 784 = 392 m-tiles x 2 oc-halves; 512 threads (8 waves: 2 oc x 4 m, 64x32 each).
// Panels: A/B = [128 rows][8 slots][16B] (BK=64); chunk (row,slot) stored at
// (row, slot^(row&7)). Staging: thread t handles LDS chunk c*512+t -> row
// 64c+(t>>3), logical slot (t&7)^((t>>3)&7): per-8-lane 128B-aligned segments.
__global__ __launch_bounds__(512, 4)
void conv_q_k(const bf16_t* __restrict__ xt, const bf16_t* __restrict__ wq,
              const float* __restrict__ ps, float* __restrict__ out) {
  __shared__ alignas(16) bf16_t Ab[2][8192];  // [buf][128 oc rows x 128B]
  __shared__ alignas(16) bf16_t Bb[2][8192];  // [buf][128 m  rows x 128B]

  const int tid  = threadIdx.x;
  const int lane = tid & 63;
  const int wave = tid >> 6;

  // interleaved XCD swizzle (784 = 8 x 98): each XCD gets 49 consecutive
  // m-tiles x both oc halves -> x slice ~3.4 MB L2-resident.
  const int bid   = blockIdx.x;
  const int s     = (bid & 7) * 98 + (bid >> 3);
  const int mt    = s >> 1;
  const int ocblk = s & 1;
  const int m0    = mt << 7;
  const int n0    = ocblk << 7;

  // ---- staging source bases (swizzled slot folded in) ----
  const int srow  = tid >> 3;                        // row within 64-row half
  const int sslot = (tid & 7) ^ (srow & 7);          // logical 16B slot
  int wA[2], xB[2];
#pragma unroll
  for (int c = 0; c < 2; ++c) {
    int row = 64 * c + srow;
    wA[c] = (n0 + row) * 2304 + sslot * 8;
    int gm = m0 + row;
    int b = gm / 3136, rem = gm - b * 3136;
    int oy = rem / 56, ox = rem - oy * 56;
    xB[c] = ((b * 58 + oy) * 58 + ox) * 256 + sslot * 8;
  }
  char* const ldA = (char*)&Ab[0][0] + (tid << 4);
  char* const ldB = (char*)&Bb[0][0] + (tid << 4);

  // ---- compute mapping: wave = (wr: 2 oc-halves) x (wc: 4 m-quarters), 64oc x 32m ----
  const int wr = wave >> 2, wc = wave & 3;
  const int rr = lane & 15, hi = lane >> 4;
  const int aRow = (wr * 64 + rr) * 128;             // byte offset of A row
  const int bRow = (wc * 32 + rr) * 128;             // byte offset of B row
  const int sx0 = ((hi)     ^ (lane & 7)) << 4;      // swizzled slot byte, ks=0
  const int sx1 = ((4 + hi) ^ (lane & 7)) << 4;      // swizzled slot byte, ks=1

  f32x4 acc[4][2], oacc[4][2];
#pragma unroll
  for (int i = 0; i < 4; ++i)
#pragma unroll
    for (int j = 0; j < 2; ++j)
#pragma unroll
      for (int k = 0; k < 4; ++k) { acc[i][j][k] = 0.f; oacc[i][j][k] = 0.f; }

  // kk in [0,36): kpos = kk>>2 (tap 0..8), ic64-block = kk&3
  auto STAGE = [&](int gg, int kk, int buf) {
    const int kpos = kk >> 2;
    const int ky = kpos / 3;
    const int kx = kpos - ky * 3;
    const int wofs = gg * 589824 + kpos * 256 + ((kk & 3) << 6);
    const int xofs = ((ky * 58 + kx) << 8) + ((kk & 3) << 6);
    char* la = ldA + buf * 16384;
    char* lb = ldB + buf * 16384;
    gload16(wq + wA[0] + wofs, la);           // A rows 0..63
    gload16(wq + wA[1] + wofs, la + 8192);    // A rows 64..127
    gload16(xt + xB[0] + xofs, lb);           // B rows 0..63
    gload16(xt + xB[1] + xofs, lb + 8192);    // B rows 64..127
  };

  STAGE(0, 0, 0);

#pragma unroll 1
  for (int g = 0; g < 4; ++g) {
#pragma unroll 2
    for (int kk = 0; kk < 36; ++kk) {
      const int buf = kk & 1;
      __syncthreads();                        // drains vmcnt: buf staged, buf^1 free
      if (kk + 1 < 36)      STAGE(g, kk + 1, buf ^ 1);
      else if (g < 3)       STAGE(g + 1, 0, buf ^ 1);
      const char* Ac = (const char*)&Ab[buf][0];
      const char* Bc = (const char*)&Bb[buf][0];
      bf16x8 av[4][2], bv[2][2];
#pragma unroll
      for (int i = 0; i < 4; ++i) {
        av[i][0] = *(const bf16x8*)(Ac + aRow + i * 2048 + sx0);
        av[i][1] = *(const bf16x8*)(Ac + aRow + i * 2048 + sx1);
      }
#pragma unroll
      for (int j = 0; j < 2; ++j) {
        bv[j][0] = *(const bf16x8*)(Bc + bRow + j * 2048 + sx0);
        bv[j][1] = *(const bf16x8*)(Bc + bRow + j * 2048 + sx1);
      }
#pragma unroll
      for (int ks = 0; ks < 2; ++ks)
#pragma unroll
        for (int i = 0; i < 4; ++i)
#pragma unroll
          for (int j = 0; j < 2; ++j)
            acc[i][j] = __builtin_amdgcn_mfma_f32_16x16x32_bf16(av[i][ks], bv[j][ks], acc[i][j], 0, 0, 0);
    }
    // per-group psum quantize, accumulate into output regs, reset psum
    const float sp  = ps[g];
    const float isp = 1.0f / sp;
#pragma unroll
    for (int i = 0; i < 4; ++i)
#pragma unroll
      for (int j = 0; j < 2; ++j)
#pragma unroll
        for (int k = 0; k < 4; ++k) {
          float q = rintf(acc[i][j][k] * isp);
          q = fminf(127.f, fmaxf(-128.f, q));
          oacc[i][j][k] += q * sp;
          acc[i][j][k] = 0.f;
        }
  }

  // ---- store: D layout col=lane&15 (m), row=(lane>>4)*4+k (oc) ----
  const int ocb = n0 + wr * 64 + (hi << 2);
#pragma unroll
  for (int j = 0; j < 2; ++j) {
    int m = m0 + wc * 32 + j * 16 + rr;
    int b = m / 3136, rem = m - b * 3136;
    int oy = rem / 56, ox = rem - oy * 56;
    int obase = b * 802816 + oy * 56 + ox;
#pragma unroll
    for (int i = 0; i < 4; ++i)
#pragma unroll
      for (int k = 0; k < 4; ++k)
        out[obase + (ocb + i * 16 + k) * 3136] = oacc[i][j][k];
  }
}

extern "C" void kernel_launch(void* const* d_in, const int* in_sizes, int n_in,
                              void* d_out, int out_size, void* d_ws, size_t ws_size,
                              hipStream_t stream) {
  const float* x   = (const float*)d_in[0];   // [16,256,56,56]
  const float* w   = (const float*)d_in[1];   // [1024,256,3,3]
  const float* wsc = (const float*)d_in[2];   // [8]
  const float* ps  = (const float*)d_in[3];   // [4]
  float* out = (float*)d_out;                 // [16,256,56,56]
  bf16_t* wq = (bf16_t*)d_ws;
  bf16_t* xt = (bf16_t*)((char*)d_ws + WS_XT_OFF);

  quant_w_k<<<9216, 256, 0, stream>>>(w, wsc, wq);
  pad_x_k<<<16 * 58, 256, 0, stream>>>(x, xt);
  conv_q_k<<<784, 512, 0, stream>>>(xt, wq, ps, out);
}

// Round 7
// 240.520 us; speedup vs baseline: 2.2551x; 1.1893x over previous
//
#include <hip/hip_runtime.h>
#include <stdint.h>
#include <stddef.h>

// SplitConv4Pim forward on MI355X.
// R7 = group-per-wave (4g x 2mpos waves, 64x64 tiles, no oacc) on R6's 2-phase
// 16-waves/CU skeleton. A panels pre-baked by P1 into per-step-contiguous,
// conflict-free chunk order; B uses both-sides XOR slot swizzle. int8 LDS
// cross-group reduction epilogue (validated in R4).
// ws layout: [wq2 bf16: 4,718,592 B][xt bf16: 27,557,888 B]

typedef __bf16 bf16_t;
typedef __bf16 bf16x8 __attribute__((ext_vector_type(8)));
typedef float  f32x4  __attribute__((ext_vector_type(4)));

#define WS_XT_OFF 4718592

__device__ __forceinline__ void gload16(const void* g, void* l) {
  __builtin_amdgcn_global_load_lds(
      (const __attribute__((address_space(1))) uint32_t*)g,
      (__attribute__((address_space(3))) uint32_t*)l, 16, 0, 0);
}

// ---- P1: weight quantization + re-layout ----
// w[o][ic][ky][kx] f32 -> wq2 panels: panel (kpos, icb32, ocb64) of 1024 16B
// chunks, chunk index = g*256 + slot*64 + row  (slot = 8-elem k sub-slot,
// row = oc within the 64-block). Panel elems = 8192; 288 panels total.
__global__ void quant_w_k(const float* __restrict__ w,
                          const float* __restrict__ wsc,
                          bf16_t* __restrict__ wqo) {
  int idx = blockIdx.x * 256 + threadIdx.x;   // 1024*9*256 threads
  int ic   = idx & 255;
  int t2   = idx >> 8;
  int kpos = t2 % 9;
  int o    = t2 / 9;
  float s  = wsc[ic >> 5];
  float wv = w[o * 2304 + ic * 9 + kpos];
  float wi = rintf(wv / s);
  wi = fminf(127.f, fmaxf(-128.f, wi));
  int u = (int)wi + 128;
  int q = (u >> 6) & 3;
  float wsplit = (float)(q * 64 - 128);
  // destination in baked layout
  int g    = o >> 8;
  int ocb  = (o >> 6) & 3;
  int row  = o & 63;
  int icb  = ic >> 5;
  int slot = (ic >> 3) & 3;
  int e    = ic & 7;
  int dst  = (((kpos * 8 + icb) * 4 + ocb) * 1024 + g * 256 + slot * 64 + row) * 8 + e;
  wqo[dst] = (bf16_t)(wsplit * s);
}

// ---- P2: x NCHW f32 -> padded NHWC bf16 xt[16][58][58][256] ----
__global__ void pad_x_k(const float* __restrict__ x, bf16_t* __restrict__ xt) {
  __shared__ bf16_t tile[56 * 258];
  int b  = blockIdx.x / 58;
  int yo = blockIdx.x % 58;
  int t  = threadIdx.x;
  bf16_t* dst = xt + (size_t)(b * 58 + yo) * 58 * 256;
  if (yo == 0 || yo == 57) {
    for (int i = 0; i < 58; ++i) dst[i * 256 + t] = (bf16_t)0.0f;
    return;
  }
  const float* src = x + (size_t)b * 256 * 3136 + (yo - 1) * 56;
  for (int i = 0; i < 56 * 256; i += 256) {
    int lin = i + t;
    int c  = lin / 56;
    int xx = lin - c * 56;
    tile[xx * 258 + c] = (bf16_t)src[c * 3136 + xx];
  }
  __syncthreads();
  for (int xo = 0; xo < 58; ++xo) {
    bf16_t v = (bf16_t)0.0f;
    if (xo >= 1 && xo <= 56) v = tile[(xo - 1) * 258 + t];
    dst[xo * 256 + t] = v;
  }
}

// ---- main conv ----
// grid 1568 = 392 m-tiles x 4 oc64-blocks; 512 threads = 8 waves (4 g x 2 mpos),
// per-wave 64m x 64oc for its group. BK=32, 72 K-steps, double-buffered 24 KB
// (A 16 KB baked panels + B 8 KB). Epilogue: int8 [4][128][64] LDS reduce.
__global__ __launch_bounds__(512, 4)
void conv_q_k(const bf16_t* __restrict__ xt, const bf16_t* __restrict__ wq2,
              const float* __restrict__ ps, float* __restrict__ out) {
  __shared__ alignas(16) char lds[2 * 24576];   // [buf][A 16KB | B 8KB]

  const int tid  = threadIdx.x;
  const int lane = tid & 63;
  const int wave = tid >> 6;
  const int g    = wave >> 1;                   // group 0..3
  const int mpos = wave & 1;                    // m half (64 rows)

  // XCD swizzle: 1568 = 8 x 196. Each XCD: 98 m-tiles x 2 oc-blocks ->
  // weight slice 2.36 MB L2-resident; consecutive u alternate ocb (x reuse).
  const int bid = blockIdx.x;
  const int xcd = bid & 7;
  const int u   = bid >> 3;                     // 0..195
  const int mt  = (xcd & 3) * 98 + (u >> 1);    // 0..391
  const int ocb = ((xcd >> 2) << 1) + (u & 1);  // 0..3
  const int m0  = mt << 7;

  // ---- B staging source (per-thread): row = tid>>2, phys slot = tid&3,
  //      logical slot = phys ^ ((row>>1)&3)  (both-sides XOR swizzle) ----
  int xB0;
  {
    int row = tid >> 2;
    int slot_log = (tid & 3) ^ ((tid >> 3) & 3);
    int gm = m0 + row;
    int b = gm / 3136, rem = gm - b * 3136;
    int oy = rem / 56, ox = rem - oy * 56;
    xB0 = ((b * 58 + oy) * 58 + ox) * 256 + slot_log * 8;
  }

  // ---- compute-side read offsets ----
  const int rr = lane & 15, hi = lane >> 4;
  const int aOff = g * 4096 + hi * 1024 + rr * 16;                    // + i*256
  const int bOff = 16384 + mpos * 4096 + rr * 64 +
                   ((hi ^ ((rr >> 1) & 3)) << 4);                     // + j*1024

  f32x4 acc[4][4];                              // [i oc-frag][j m-frag]
#pragma unroll
  for (int i = 0; i < 4; ++i)
#pragma unroll
    for (int j = 0; j < 4; ++j)
#pragma unroll
      for (int k = 0; k < 4; ++k) acc[i][j][k] = 0.f;

  // kk in [0,72): kpos = kk>>3 (tap), icb = kk&7 (32-ic block)
  auto STAGE = [&](int kk, int buf) {
    const int kpos = kk >> 3, icb = kk & 7;
    const int ky = kpos / 3, kx = kpos - ky * 3;
    const int sA = ((kpos * 8 + icb) * 4 + ocb) * 8192;   // panel elem base
    char* base = lds + buf * 24576;
    gload16(wq2 + sA + tid * 8,        base + tid * 16);         // A chunks 0..511
    gload16(wq2 + sA + 4096 + tid * 8, base + 8192 + tid * 16);  // A chunks 512..1023
    gload16(xt + xB0 + ((ky * 58 + kx) << 8) + icb * 32,
            base + 16384 + tid * 16);                            // B
  };

  auto body = [&](int kk, int buf) {
    __syncthreads();                            // drains vmcnt: buf staged, buf^1 free
    if (kk + 1 < 72) STAGE(kk + 1, buf ^ 1);
    const char* bp = lds + buf * 24576;
    bf16x8 av[4], bv[4];
#pragma unroll
    for (int i = 0; i < 4; ++i) av[i] = *(const bf16x8*)(bp + aOff + i * 256);
#pragma unroll
    for (int j = 0; j < 4; ++j) bv[j] = *(const bf16x8*)(bp + bOff + j * 1024);
#pragma unroll
    for (int i = 0; i < 4; ++i)
#pragma unroll
      for (int j = 0; j < 4; ++j)
        acc[i][j] = __builtin_amdgcn_mfma_f32_16x16x32_bf16(av[i], bv[j], acc[i][j], 0, 0, 0);
  };

  STAGE(0, 0);
#pragma unroll 1
  for (int tt = 0; tt < 36; ++tt) {
    body(2 * tt,     0);
    body(2 * tt + 1, 1);
  }
  __syncthreads();                              // all reads done; lds reusable

  // ---- epilogue: quantize own group's psum -> int8 -> LDS [4][128][64] ----
  {
    const float sp  = ps[g];
    const float isp = 1.0f / sp;
#pragma unroll
    for (int i = 0; i < 4; ++i)
#pragma unroll
      for (int j = 0; j < 4; ++j) {
        uint32_t pk = 0;
#pragma unroll
        for (int k = 0; k < 4; ++k) {
          float q = rintf(acc[i][j][k] * isp);
          q = fminf(127.f, fmaxf(-128.f, q));
          pk |= ((uint32_t)(((int)q) & 255)) << (8 * k);
        }
        int m_l  = mpos * 64 + j * 16 + rr;
        int oc_l = i * 16 + (hi << 2);
        *(uint32_t*)(lds + g * 8192 + m_l * 64 + oc_l) = pk;
      }
  }
  __syncthreads();
  {
    const int m_l = tid >> 2;                   // 0..127
    const int och = (tid & 3) << 4;             // 0/16/32/48
    float o[16];
#pragma unroll
    for (int j = 0; j < 16; ++j) o[j] = 0.f;
#pragma unroll
    for (int gg = 0; gg < 4; ++gg) {
      const float spg = ps[gg];
      const char* rp = lds + gg * 8192 + m_l * 64 + och;
#pragma unroll
      for (int w4 = 0; w4 < 4; ++w4) {
        uint32_t v = *(const uint32_t*)(rp + w4 * 4);
#pragma unroll
        for (int b2 = 0; b2 < 4; ++b2)
          o[w4 * 4 + b2] += (float)((int)(int8_t)(v >> (8 * b2))) * spg;
      }
    }
    int gm = m0 + m_l;
    int b = gm / 3136, rem = gm - b * 3136;
    int oy = rem / 56, ox = rem - oy * 56;
    float* ob = out + b * 802816 + oy * 56 + ox;
    const int occ = (ocb << 6) + och;
#pragma unroll
    for (int j = 0; j < 16; ++j) ob[(occ + j) * 3136] = o[j];
  }
}

extern "C" void kernel_launch(void* const* d_in, const int* in_sizes, int n_in,
                              void* d_out, int out_size, void* d_ws, size_t ws_size,
                              hipStream_t stream) {
  const float* x   = (const float*)d_in[0];   // [16,256,56,56]
  const float* w   = (const float*)d_in[1];   // [1024,256,3,3]
  const float* wsc = (const float*)d_in[2];   // [8]
  const float* ps  = (const float*)d_in[3];   // [4]
  float* out = (float*)d_out;                 // [16,256,56,56]
  bf16_t* wq2 = (bf16_t*)d_ws;
  bf16_t* xt  = (bf16_t*)((char*)d_ws + WS_XT_OFF);

  quant_w_k<<<9216, 256, 0, stream>>>(w, wsc, wq2);
  pad_x_k<<<16 * 58, 256, 0, stream>>>(x, xt);
  conv_q_k<<<1568, 512, 0, stream>>>(xt, wq2, ps, out);
}

// Round 8
// 231.183 us; speedup vs baseline: 2.3462x; 1.0404x over previous
//
#include <hip/hip_runtime.h>
#include <stdint.h>
#include <stddef.h>

// SplitConv4Pim forward on MI355X.
// R8 = R7's group-per-wave geometry (4g x 2mpos waves, 64x64 tiles, baked A
// panels, XOR-swizzled B, int8 LDS group-reduce) + T3/T4 counted-vmcnt
// triple-buffer pipeline (never vmcnt(0) in main loop) + T5 setprio.
// ws layout: [wq2 bf16: 4,718,592 B][xt bf16: 27,557,888 B]

typedef __bf16 bf16_t;
typedef __bf16 bf16x8 __attribute__((ext_vector_type(8)));
typedef float  f32x4  __attribute__((ext_vector_type(4)));

#define WS_XT_OFF 4718592

__device__ __forceinline__ void gload16(const void* g, void* l) {
  __builtin_amdgcn_global_load_lds(
      (const __attribute__((address_space(1))) uint32_t*)g,
      (__attribute__((address_space(3))) uint32_t*)l, 16, 0, 0);
}

// ---- P1: weight quantization + re-layout ----
// w[o][ic][ky][kx] f32 -> wq2 panels: panel (kpos, icb32, ocb64) of 1024 16B
// chunks, chunk index = g*256 + slot*64 + row. Panel elems = 8192; 288 panels.
__global__ void quant_w_k(const float* __restrict__ w,
                          const float* __restrict__ wsc,
                          bf16_t* __restrict__ wqo) {
  int idx = blockIdx.x * 256 + threadIdx.x;   // 1024*9*256 threads
  int ic   = idx & 255;
  int t2   = idx >> 8;
  int kpos = t2 % 9;
  int o    = t2 / 9;
  float s  = wsc[ic >> 5];
  float wv = w[o * 2304 + ic * 9 + kpos];
  float wi = rintf(wv / s);
  wi = fminf(127.f, fmaxf(-128.f, wi));
  int u = (int)wi + 128;
  int q = (u >> 6) & 3;
  float wsplit = (float)(q * 64 - 128);
  int g    = o >> 8;
  int ocb  = (o >> 6) & 3;
  int row  = o & 63;
  int icb  = ic >> 5;
  int slot = (ic >> 3) & 3;
  int e    = ic & 7;
  int dst  = (((kpos * 8 + icb) * 4 + ocb) * 1024 + g * 256 + slot * 64 + row) * 8 + e;
  wqo[dst] = (bf16_t)(wsplit * s);
}

// ---- P2: x NCHW f32 -> padded NHWC bf16 xt[16][58][58][256] ----
__global__ void pad_x_k(const float* __restrict__ x, bf16_t* __restrict__ xt) {
  __shared__ bf16_t tile[56 * 258];
  int b  = blockIdx.x / 58;
  int yo = blockIdx.x % 58;
  int t  = threadIdx.x;
  bf16_t* dst = xt + (size_t)(b * 58 + yo) * 58 * 256;
  if (yo == 0 || yo == 57) {
    for (int i = 0; i < 58; ++i) dst[i * 256 + t] = (bf16_t)0.0f;
    return;
  }
  const float* src = x + (size_t)b * 256 * 3136 + (yo - 1) * 56;
  for (int i = 0; i < 56 * 256; i += 256) {
    int lin = i + t;
    int c  = lin / 56;
    int xx = lin - c * 56;
    tile[xx * 258 + c] = (bf16_t)src[c * 3136 + xx];
  }
  __syncthreads();
  for (int xo = 0; xo < 58; ++xo) {
    bf16_t v = (bf16_t)0.0f;
    if (xo >= 1 && xo <= 56) v = tile[(xo - 1) * 258 + t];
    dst[xo * 256 + t] = v;
  }
}

// ---- main conv ----
// grid 1568 = 392 m-tiles x 4 oc64-blocks; 512 threads = 8 waves (4 g x 2 mpos),
// per-wave 64m x 64oc for its group. BK=32, 72 K-steps, TRIPLE-buffered 24 KB
// step buffers (72 KB -> 2 blocks/CU), depth-2 prefetch, counted vmcnt(3).
__global__ __launch_bounds__(512, 4)
void conv_q_k(const bf16_t* __restrict__ xt, const bf16_t* __restrict__ wq2,
              const float* __restrict__ ps, float* __restrict__ out) {
  __shared__ alignas(16) char lds[3 * 24576];   // [buf][A 16KB | B 8KB]

  const int tid  = threadIdx.x;
  const int lane = tid & 63;
  const int wave = tid >> 6;
  const int g    = wave >> 1;                   // group 0..3
  const int mpos = wave & 1;                    // m half (64 rows)

  // XCD swizzle: 1568 = 8 x 196. Each XCD: 98 m-tiles x 2 oc-blocks ->
  // weight slice 2.36 MB L2-resident; consecutive u alternate ocb (x reuse).
  const int bid = blockIdx.x;
  const int xcd = bid & 7;
  const int u   = bid >> 3;                     // 0..195
  const int mt  = (xcd & 3) * 98 + (u >> 1);    // 0..391
  const int ocb = ((xcd >> 2) << 1) + (u & 1);  // 0..3
  const int m0  = mt << 7;

  // ---- B staging source: row = tid>>2, phys slot = tid&3,
  //      logical slot = phys ^ ((row>>1)&3)  (both-sides XOR swizzle) ----
  int xB0;
  {
    int row = tid >> 2;
    int slot_log = (tid & 3) ^ ((tid >> 3) & 3);
    int gm = m0 + row;
    int b = gm / 3136, rem = gm - b * 3136;
    int oy = rem / 56, ox = rem - oy * 56;
    xB0 = ((b * 58 + oy) * 58 + ox) * 256 + slot_log * 8;
  }

  // ---- compute-side read offsets ----
  const int rr = lane & 15, hi = lane >> 4;
  const int aOff = g * 4096 + hi * 1024 + rr * 16;                    // + i*256
  const int bOff = 16384 + mpos * 4096 + rr * 64 +
                   ((hi ^ ((rr >> 1) & 3)) << 4);                     // + j*1024

  f32x4 acc[4][4];                              // [i oc-frag][j m-frag]
#pragma unroll
  for (int i = 0; i < 4; ++i)
#pragma unroll
    for (int j = 0; j < 4; ++j)
#pragma unroll
      for (int k = 0; k < 4; ++k) acc[i][j][k] = 0.f;

  // kk in [0,72): kpos = kk>>3 (tap), icb = kk&7 (32-ic block)
  auto STAGE = [&](int kk, int buf) {
    const int kpos = kk >> 3, icb = kk & 7;
    const int ky = kpos / 3, kx = kpos - ky * 3;
    const int sA = ((kpos * 8 + icb) * 4 + ocb) * 8192;   // panel elem base
    char* base = lds + buf * 24576;
    gload16(wq2 + sA + tid * 8,        base + tid * 16);         // A chunks 0..511
    gload16(wq2 + sA + 4096 + tid * 8, base + 8192 + tid * 16);  // A chunks 512..1023
    gload16(xt + xB0 + ((ky * 58 + kx) << 8) + icb * 32,
            base + 16384 + tid * 16);                            // B
  };

  // counted-vmcnt body: STAGE(t+2) first, MFMA, then wait tile t+1 (3 newest
  // loads = tile t+2 stay in flight), barrier. Never vmcnt(0) mid-loop.
  auto body = [&](int t, int cur, int nxt, bool pf, bool tail) {
    if (pf) STAGE(t + 2, nxt);
    const char* bp = lds + cur * 24576;
    bf16x8 av[4], bv[4];
#pragma unroll
    for (int i = 0; i < 4; ++i) av[i] = *(const bf16x8*)(bp + aOff + i * 256);
#pragma unroll
    for (int j = 0; j < 4; ++j) bv[j] = *(const bf16x8*)(bp + bOff + j * 1024);
    __builtin_amdgcn_s_setprio(1);
#pragma unroll
    for (int i = 0; i < 4; ++i)
#pragma unroll
      for (int j = 0; j < 4; ++j)
        acc[i][j] = __builtin_amdgcn_mfma_f32_16x16x32_bf16(av[i], bv[j], acc[i][j], 0, 0, 0);
    __builtin_amdgcn_s_setprio(0);
    if (tail) asm volatile("s_waitcnt vmcnt(0)" ::: "memory");
    else      asm volatile("s_waitcnt vmcnt(3)" ::: "memory");
    __builtin_amdgcn_s_barrier();
    __builtin_amdgcn_sched_barrier(0);
    asm volatile("" ::: "memory");
  };

  // prologue: stage tiles 0,1; wait tile 0 (tile 1's 3 loads stay in flight)
  STAGE(0, 0); STAGE(1, 1);
  asm volatile("s_waitcnt vmcnt(3)" ::: "memory");
  __builtin_amdgcn_s_barrier();
  __builtin_amdgcn_sched_barrier(0);

#pragma unroll 1
  for (int tt = 0; tt < 23; ++tt) {
    body(3 * tt,     0, 2, true, false);
    body(3 * tt + 1, 1, 0, true, false);
    body(3 * tt + 2, 2, 1, true, false);
  }
  body(69, 0, 2, true,  false);   // stages tile 71; waits tile 70
  body(70, 1, 0, false, true);    // drains tile 71
  body(71, 2, 1, false, true);
  __syncthreads();                // lds reusable

  // ---- epilogue: quantize own group's psum -> int8 -> LDS [4][128][64] ----
  {
    const float sp  = ps[g];
    const float isp = 1.0f / sp;
#pragma unroll
    for (int i = 0; i < 4; ++i)
#pragma unroll
      for (int j = 0; j < 4; ++j) {
        uint32_t pk = 0;
#pragma unroll
        for (int k = 0; k < 4; ++k) {
          float q = rintf(acc[i][j][k] * isp);
          q = fminf(127.f, fmaxf(-128.f, q));
          pk |= ((uint32_t)(((int)q) & 255)) << (8 * k);
        }
        int m_l  = mpos * 64 + j * 16 + rr;
        int oc_l = i * 16 + (hi << 2);
        *(uint32_t*)(lds + g * 8192 + m_l * 64 + oc_l) = pk;
      }
  }
  __syncthreads();
  {
    const int m_l = tid >> 2;                   // 0..127
    const int och = (tid & 3) << 4;             // 0/16/32/48
    float o[16];
#pragma unroll
    for (int j = 0; j < 16; ++j) o[j] = 0.f;
#pragma unroll
    for (int gg = 0; gg < 4; ++gg) {
      const float spg = ps[gg];
      const char* rp = lds + gg * 8192 + m_l * 64 + och;
#pragma unroll
      for (int w4 = 0; w4 < 4; ++w4) {
        uint32_t v = *(const uint32_t*)(rp + w4 * 4);
#pragma unroll
        for (int b2 = 0; b2 < 4; ++b2)
          o[w4 * 4 + b2] += (float)((int)(int8_t)(v >> (8 * b2))) * spg;
      }
    }
    int gm = m0 + m_l;
    int b = gm / 3136, rem = gm - b * 3136;
    int oy = rem / 56, ox = rem - oy * 56;
    float* ob = out + b * 802816 + oy * 56 + ox;
    const int occ = (ocb << 6) + och;
#pragma unroll
    for (int j = 0; j < 16; ++j) ob[(occ + j) * 3136] = o[j];
  }
}

extern "C" void kernel_launch(void* const* d_in, const int* in_sizes, int n_in,
                              void* d_out, int out_size, void* d_ws, size_t ws_size,
                              hipStream_t stream) {
  const float* x   = (const float*)d_in[0];   // [16,256,56,56]
  const float* w   = (const float*)d_in[1];   // [1024,256,3,3]
  const float* wsc = (const float*)d_in[2];   // [8]
  const float* ps  = (const float*)d_in[3];   // [4]
  float* out = (float*)d_out;                 // [16,256,56,56]
  bf16_t* wq2 = (bf16_t*)d_ws;
  bf16_t* xt  = (bf16_t*)((char*)d_ws + WS_XT_OFF);

  quant_w_k<<<9216, 256, 0, stream>>>(w, wsc, wq2);
  pad_x_k<<<16 * 58, 256, 0, stream>>>(x, xt);
  conv_q_k<<<1568, 512, 0, stream>>>(xt, wq2, ps, out);
}

// Round 9
// 230.347 us; speedup vs baseline: 2.3547x; 1.0036x over previous
//
#include <hip/hip_runtime.h>
#include <stdint.h>
#include <stddef.h>

// SplitConv4Pim forward on MI355X.
// R9 = R8's group-per-wave staging (baked A panels, XOR-swizzled B, counted
// vmcnt triple-buffer) with 128m x 64oc wave tiles: 4 waves/block (one per
// group), A read 1x / B read 4x -> 23 B/kFLOP LDS reads. 2 blocks/CU.
// P1+P2 fused into one launch.
// ws layout: [wq2 bf16: 4,718,592 B][xt bf16: 27,557,888 B]

typedef __bf16 bf16_t;
typedef __bf16 bf16x8 __attribute__((ext_vector_type(8)));
typedef float  f32x4  __attribute__((ext_vector_type(4)));

#define WS_XT_OFF 4718592

__device__ __forceinline__ void gload16(const void* g, void* l) {
  __builtin_amdgcn_global_load_lds(
      (const __attribute__((address_space(1))) uint32_t*)g,
      (__attribute__((address_space(3))) uint32_t*)l, 16, 0, 0);
}

// ---- P1+P2 fused: weight quantize+re-layout (blocks 0..9215) and
//      x NCHW f32 -> padded NHWC bf16 (blocks 9216..10143) ----
__global__ void prep_k(const float* __restrict__ w, const float* __restrict__ wsc,
                       bf16_t* __restrict__ wqo,
                       const float* __restrict__ x, bf16_t* __restrict__ xt) {
  __shared__ bf16_t tile[56 * 258];
  if (blockIdx.x < 9216) {
    // quant: w[o][ic][ky][kx] -> wq2 panel (kpos,icb32,ocb64): 1024 chunks,
    // chunk = g*256 + slot*64 + row.
    int idx = blockIdx.x * 256 + threadIdx.x;
    int ic   = idx & 255;
    int t2   = idx >> 8;
    int kpos = t2 % 9;
    int o    = t2 / 9;
    float s  = wsc[ic >> 5];
    float wv = w[o * 2304 + ic * 9 + kpos];
    float wi = rintf(wv / s);
    wi = fminf(127.f, fmaxf(-128.f, wi));
    int u = (int)wi + 128;
    int q = (u >> 6) & 3;
    float wsplit = (float)(q * 64 - 128);
    int g    = o >> 8;
    int ocb  = (o >> 6) & 3;
    int row  = o & 63;
    int icb  = ic >> 5;
    int slot = (ic >> 3) & 3;
    int e    = ic & 7;
    int dst  = (((kpos * 8 + icb) * 4 + ocb) * 1024 + g * 256 + slot * 64 + row) * 8 + e;
    wqo[dst] = (bf16_t)(wsplit * s);
    return;
  }
  int pb = blockIdx.x - 9216;                 // 0..927
  int b  = pb / 58;
  int yo = pb % 58;
  int t  = threadIdx.x;
  bf16_t* dst = xt + (size_t)(b * 58 + yo) * 58 * 256;
  if (yo == 0 || yo == 57) {
    for (int i = 0; i < 58; ++i) dst[i * 256 + t] = (bf16_t)0.0f;
    return;
  }
  const float* src = x + (size_t)b * 256 * 3136 + (yo - 1) * 56;
  for (int i = 0; i < 56 * 256; i += 256) {
    int lin = i + t;
    int c  = lin / 56;
    int xx = lin - c * 56;
    tile[xx * 258 + c] = (bf16_t)src[c * 3136 + xx];
  }
  __syncthreads();
  for (int xo = 0; xo < 58; ++xo) {
    bf16_t v = (bf16_t)0.0f;
    if (xo >= 1 && xo <= 56) v = tile[(xo - 1) * 258 + t];
    dst[xo * 256 + t] = v;
  }
}

// ---- main conv ----
// grid 1568 = 392 m-tiles x 4 oc64-blocks; 256 threads = 4 waves, wave g owns
// group g's full 128m x 64oc psum (acc 128 regs). BK=32, 72 K-steps,
// triple-buffered 24 KB (A 16 KB baked + B 8 KB), depth-2 prefetch, vmcnt(6).
__global__ __launch_bounds__(256, 2)
void conv_q_k(const bf16_t* __restrict__ xt, const bf16_t* __restrict__ wq2,
              const float* __restrict__ ps, float* __restrict__ out) {
  __shared__ alignas(16) char lds[3 * 24576];   // [buf][A 16KB | B 8KB]

  const int tid  = threadIdx.x;
  const int lane = tid & 63;
  const int g    = tid >> 6;                    // wave = group 0..3

  // XCD swizzle: 1568 = 8 x 196. Each XCD: 98 m-tiles x 2 oc-blocks.
  const int bid = blockIdx.x;
  const int xcd = bid & 7;
  const int u   = bid >> 3;                     // 0..195
  const int mt  = (xcd & 3) * 98 + (u >> 1);    // 0..391
  const int ocb = ((xcd >> 2) << 1) + (u & 1);  // 0..3
  const int m0  = mt << 7;

  // ---- B staging sources: chunk ci = c*256+tid (c=0,1): row = ci>>2,
  //      phys slot = ci&3, logical slot = phys ^ ((row>>1)&3) ----
  int xB[2];
#pragma unroll
  for (int c = 0; c < 2; ++c) {
    int row = c * 64 + (tid >> 2);
    int slot_log = (tid & 3) ^ ((row >> 1) & 3);
    int gm = m0 + row;
    int b = gm / 3136, rem = gm - b * 3136;
    int oy = rem / 56, ox = rem - oy * 56;
    xB[c] = ((b * 58 + oy) * 58 + ox) * 256 + slot_log * 8;
  }

  // ---- compute-side read offsets ----
  const int rr = lane & 15, hi = lane >> 4;
  const int aOff = g * 4096 + hi * 1024 + rr * 16;          // + i*256
  const int bOff = 16384 + rr * 64 + ((hi ^ ((rr >> 1) & 3)) << 4);  // + j*1024

  f32x4 acc[4][8];                              // [i oc-frag][j m-frag]
#pragma unroll
  for (int i = 0; i < 4; ++i)
#pragma unroll
    for (int j = 0; j < 8; ++j)
#pragma unroll
      for (int k = 0; k < 4; ++k) acc[i][j][k] = 0.f;

  // kk in [0,72): kpos = kk>>3 (tap), icb = kk&7 (32-ic block)
  auto STAGE = [&](int kk, int buf) {
    const int kpos = kk >> 3, icb = kk & 7;
    const int ky = kpos / 3, kx = kpos - ky * 3;
    const int sA = ((kpos * 8 + icb) * 4 + ocb) * 8192;   // panel elem base
    const int xof = ((ky * 58 + kx) << 8) + icb * 32;
    char* base = lds + buf * 24576;
#pragma unroll
    for (int c = 0; c < 4; ++c)                 // A: 16 KB = 4 calls
      gload16(wq2 + sA + c * 2048 + tid * 8, base + c * 4096 + tid * 16);
#pragma unroll
    for (int c = 0; c < 2; ++c)                 // B: 8 KB = 2 calls
      gload16(xt + xB[c] + xof, base + 16384 + c * 4096 + tid * 16);
  };

  // counted-vmcnt body: STAGE(t+2), MFMA on t, wait tile t+1 (6 newest = t+2
  // stay in flight), barrier. Never vmcnt(0) mid-loop.
  auto body = [&](int t, int cur, int nxt, bool pf, bool tail) {
    if (pf) STAGE(t + 2, nxt);
    const char* bp = lds + cur * 24576;
    bf16x8 av[4], bv[8];
#pragma unroll
    for (int i = 0; i < 4; ++i) av[i] = *(const bf16x8*)(bp + aOff + i * 256);
#pragma unroll
    for (int j = 0; j < 8; ++j) bv[j] = *(const bf16x8*)(bp + bOff + j * 1024);
    __builtin_amdgcn_s_setprio(1);
#pragma unroll
    for (int i = 0; i < 4; ++i)
#pragma unroll
      for (int j = 0; j < 8; ++j)
        acc[i][j] = __builtin_amdgcn_mfma_f32_16x16x32_bf16(av[i], bv[j], acc[i][j], 0, 0, 0);
    __builtin_amdgcn_s_setprio(0);
    if (tail) asm volatile("s_waitcnt vmcnt(0)" ::: "memory");
    else      asm volatile("s_waitcnt vmcnt(6)" ::: "memory");
    __builtin_amdgcn_s_barrier();
    __builtin_amdgcn_sched_barrier(0);
    asm volatile("" ::: "memory");
  };

  // prologue: stage tiles 0,1; wait tile 0 (tile 1's 6 loads stay in flight)
  STAGE(0, 0); STAGE(1, 1);
  asm volatile("s_waitcnt vmcnt(6)" ::: "memory");
  __builtin_amdgcn_s_barrier();
  __builtin_amdgcn_sched_barrier(0);

#pragma unroll 1
  for (int tt = 0; tt < 23; ++tt) {
    body(3 * tt,     0, 2, true, false);
    body(3 * tt + 1, 1, 0, true, false);
    body(3 * tt + 2, 2, 1, true, false);
  }
  body(69, 0, 2, true,  false);   // stages tile 71; waits tile 70
  body(70, 1, 0, false, true);    // drains tile 71
  body(71, 2, 1, false, true);
  __syncthreads();                // lds reusable

  // ---- epilogue: quantize own group's psum -> int8 -> LDS [4][128][64] ----
  {
    const float sp  = ps[g];
    const float isp = 1.0f / sp;
#pragma unroll
    for (int i = 0; i < 4; ++i)
#pragma unroll
      for (int j = 0; j < 8; ++j) {
        uint32_t pk = 0;
#pragma unroll
        for (int k = 0; k < 4; ++k) {
          float q = rintf(acc[i][j][k] * isp);
          q = fminf(127.f, fmaxf(-128.f, q));
          pk |= ((uint32_t)(((int)q) & 255)) << (8 * k);
        }
        int m_l  = j * 16 + rr;
        int oc_l = i * 16 + (hi << 2);
        *(uint32_t*)(lds + g * 8192 + m_l * 64 + oc_l) = pk;
      }
  }
  __syncthreads();
  {
    const int m_l = tid >> 1;                   // 0..127
    const int och = (tid & 1) << 5;             // 0/32
    float o[32];
#pragma unroll
    for (int j = 0; j < 32; ++j) o[j] = 0.f;
#pragma unroll
    for (int gg = 0; gg < 4; ++gg) {
      const float spg = ps[gg];
      const char* rp = lds + gg * 8192 + m_l * 64 + och;
#pragma unroll
      for (int w4 = 0; w4 < 8; ++w4) {
        uint32_t v = *(const uint32_t*)(rp + w4 * 4);
#pragma unroll
        for (int b2 = 0; b2 < 4; ++b2)
          o[w4 * 4 + b2] += (float)((int)(int8_t)(v >> (8 * b2))) * spg;
      }
    }
    int gm = m0 + m_l;
    int b = gm / 3136, rem = gm - b * 3136;
    int oy = rem / 56, ox = rem - oy * 56;
    float* ob = out + b * 802816 + oy * 56 + ox;
    const int occ = (ocb << 6) + och;
#pragma unroll
    for (int j = 0; j < 32; ++j) ob[(occ + j) * 3136] = o[j];
  }
}

extern "C" void kernel_launch(void* const* d_in, const int* in_sizes, int n_in,
                              void* d_out, int out_size, void* d_ws, size_t ws_size,
                              hipStream_t stream) {
  const float* x   = (const float*)d_in[0];   // [16,256,56,56]
  const float* w   = (const float*)d_in[1];   // [1024,256,3,3]
  const float* wsc = (const float*)d_in[2];   // [8]
  const float* ps  = (const float*)d_in[3];   // [4]
  float* out = (float*)d_out;                 // [16,256,56,56]
  bf16_t* wq2 = (bf16_t*)d_ws;
  bf16_t* xt  = (bf16_t*)((char*)d_ws + WS_XT_OFF);

  prep_k<<<9216 + 928, 256, 0, stream>>>(w, wsc, wq2, x, xt);
  conv_q_k<<<1568, 256, 0, stream>>>(xt, wq2, ps, out);
}